// Round 10
// baseline (406.568 us; speedup 1.0000x reference)
//
#include <hip/hip_runtime.h>
#include <hip/hip_cooperative_groups.h>

namespace cg = cooperative_groups;

typedef __attribute__((ext_vector_type(8))) short short8;
typedef __attribute__((ext_vector_type(4))) float f32x4;

__device__ __forceinline__ unsigned short f2bf(float f) {
    unsigned u = __float_as_uint(f);
    u += 0x7FFF + ((u >> 16) & 1);          // round-to-nearest-even
    return (unsigned short)(u >> 16);
}

__device__ __forceinline__ float readlane_f(float v, int l) {
    return __int_as_float(__builtin_amdgcn_readlane(__float_as_int(v), l));
}

__device__ __forceinline__ float bflo(unsigned u) { return __uint_as_float(u << 16); }
__device__ __forceinline__ float bfhi(unsigned u) { return __uint_as_float(u & 0xFFFF0000u); }

// ---------------------------------------------------------------------------
// 1) ONE cooperative prep kernel: zero+casts | hist | block scan | base fix |
//    scatter.  Every phase uses the full grid (256 blocks x 1024 thr).
// ---------------------------------------------------------------------------
__global__ __launch_bounds__(1024) void prep_kernel(
    const float* __restrict__ X, const float* __restrict__ W,
    const float* __restrict__ W0,
    const int* __restrict__ esrc, const int* __restrict__ edst,
    const int* __restrict__ erel,
    unsigned short* __restrict__ Xb, unsigned short* __restrict__ Bt,
    int* __restrict__ counts, int* __restrict__ offsets,
    int* __restrict__ blockSums, unsigned* __restrict__ sorted,
    int N, int E, int R)
{
    cg::grid_group grid = cg::this_grid();
    __shared__ int sd[1024];
    const int tid = (int)(blockIdx.x * 1024 + threadIdx.x);
    const int nthreads = (int)(gridDim.x * 1024);
    const int t = (int)threadIdx.x;
    const int ktot = (R + 1) * 128;

    // ---- phase 0: zero counts + cast X->Xb and [W;W0]^T->Bt ----
    for (int i = tid; i < N; i += nthreads) counts[i] = 0;
    const int nx = N * 32;                       // float4 chunks of X
    for (int i = tid; i < nx; i += nthreads) {
        const float4 v = ((const float4*)X)[i];
        uint2 p;
        p.x = (unsigned)f2bf(v.x) | ((unsigned)f2bf(v.y) << 16);
        p.y = (unsigned)f2bf(v.z) | ((unsigned)f2bf(v.w) << 16);
        *(uint2*)(Xb + (size_t)i * 4) = p;
    }
    for (int i = tid; i < 128 * ktot; i += nthreads) {
        const int n = i / ktot;
        const int k = i - n * ktot;
        const float v = (k < R * 128) ? W[(size_t)k * 128 + n]
                                      : W0[(size_t)(k - R * 128) * 128 + n];
        Bt[(size_t)n * ktot + k] = f2bf(v);
    }
    grid.sync();

    // ---- phase 1: histogram over dst ----
    for (int i = tid; i < E; i += nthreads) atomicAdd(&counts[edst[i]], 1);
    grid.sync();

    // ---- phase 2: block-local exclusive scan of this block's bin chunk ----
    const int C = (N + (int)gridDim.x - 1) / (int)gridDim.x;   // bins/block
    const int base = (int)blockIdx.x * C;
    int v = 0;
    if (t < C && base + t < N) v = counts[base + t];
    sd[t] = v; __syncthreads();
    for (int off = 1; off < 1024; off <<= 1) {
        int x = (t >= off) ? sd[t - off] : 0;
        __syncthreads();
        sd[t] += x;
        __syncthreads();
    }
    const int locEx = sd[t] - v;                 // exclusive local prefix
    if (t == 1023) blockSums[blockIdx.x] = sd[1023];
    grid.sync();

    // ---- phase 3: every block sums blockSums[0..blockIdx) -> base; write offsets
    {
        int bv = 0;
        if (t < (int)blockIdx.x) bv = blockSums[t];   // gridDim.x <= 1024
        sd[t] = bv; __syncthreads();
        for (int off = 512; off > 0; off >>= 1) {
            if (t < off) sd[t] += sd[t + off];
            __syncthreads();
        }
        const int bbase = sd[0];
        if (t < C && base + t < N) offsets[base + t] = locEx + bbase;
    }
    grid.sync();

    // ---- phase 4: scatter (rel<<28)|src into dst-sorted order ----
    for (int i = tid; i < E; i += nthreads) {
        const int pos = atomicAdd(&offsets[edst[i]], 1);
        sorted[pos] = (unsigned)esrc[i] | ((unsigned)erel[i] << 28);
    }
}

// ---------------------------------------------------------------------------
// 2) dst-major aggregate, one wave per dst. Edges carried as (rel<<28)|src;
//    readlane -> SGPR, switch(rel) uniform scalar branch, named-VGPR accs.
//    Writes A row of R*128 bf16 (self segment read from Xb by the GEMM).
// ---------------------------------------------------------------------------
#define ACC(P, U) switch ((P) >> 28) {                                   \
        case 0: ax0 += bflo(U); ay0 += bfhi(U); break;                   \
        case 1: ax1 += bflo(U); ay1 += bfhi(U); break;                   \
        case 2: ax2 += bflo(U); ay2 += bfhi(U); break;                   \
        case 3: ax3 += bflo(U); ay3 += bfhi(U); break;                   \
        case 4: ax4 += bflo(U); ay4 += bfhi(U); break;                   \
        case 5: ax5 += bflo(U); ay5 += bfhi(U); break;                   \
        case 6: ax6 += bflo(U); ay6 += bfhi(U); break;                   \
        default: ax7 += bflo(U); ay7 += bfhi(U); break; }

__global__ __launch_bounds__(256) void aggregate_kernel(
    const unsigned short* __restrict__ Xb, const float* __restrict__ inv_norm,
    const unsigned* __restrict__ sorted, const int* __restrict__ counts,
    const int* __restrict__ bucket_end, unsigned short* __restrict__ A,
    int N)
{
    const int dst = (int)((blockIdx.x * blockDim.x + threadIdx.x) >> 6);
    if (dst >= N) return;
    const int lane = threadIdx.x & 63;

    const int end = bucket_end[dst];
    const int start = end - counts[dst];

    float ax0=0,ay0=0, ax1=0,ay1=0, ax2=0,ay2=0, ax3=0,ay3=0;
    float ax4=0,ay4=0, ax5=0,ay5=0, ax6=0,ay6=0, ax7=0,ay7=0;

    for (int cb = start; cb < end; cb += 64) {
        const int take = min(64, end - cb);
        unsigned batch = 0;
        if (cb + lane < end) batch = sorted[cb + lane];
        int j = 0;
        for (; j + 8 <= take; j += 8) {
            unsigned p[8], u[8];
#pragma unroll
            for (int q = 0; q < 8; ++q)
                p[q] = (unsigned)__builtin_amdgcn_readlane((int)batch, j + q);
#pragma unroll
            for (int q = 0; q < 8; ++q)
                u[q] = ((const unsigned*)(Xb + ((size_t)(p[q] & 0x0FFFFFFFu) << 7)))[lane];
            ACC(p[0], u[0]); ACC(p[1], u[1]); ACC(p[2], u[2]); ACC(p[3], u[3]);
            ACC(p[4], u[4]); ACC(p[5], u[5]); ACC(p[6], u[6]); ACC(p[7], u[7]);
        }
        for (; j + 4 <= take; j += 4) {
            const unsigned p0 = (unsigned)__builtin_amdgcn_readlane((int)batch, j);
            const unsigned p1 = (unsigned)__builtin_amdgcn_readlane((int)batch, j + 1);
            const unsigned p2 = (unsigned)__builtin_amdgcn_readlane((int)batch, j + 2);
            const unsigned p3 = (unsigned)__builtin_amdgcn_readlane((int)batch, j + 3);
            const unsigned u0 = ((const unsigned*)(Xb + ((size_t)(p0 & 0x0FFFFFFFu) << 7)))[lane];
            const unsigned u1 = ((const unsigned*)(Xb + ((size_t)(p1 & 0x0FFFFFFFu) << 7)))[lane];
            const unsigned u2 = ((const unsigned*)(Xb + ((size_t)(p2 & 0x0FFFFFFFu) << 7)))[lane];
            const unsigned u3 = ((const unsigned*)(Xb + ((size_t)(p3 & 0x0FFFFFFFu) << 7)))[lane];
            ACC(p0, u0); ACC(p1, u1); ACC(p2, u2); ACC(p3, u3);
        }
        for (; j < take; ++j) {
            const unsigned p = (unsigned)__builtin_amdgcn_readlane((int)batch, j);
            const unsigned u = ((const unsigned*)(Xb + ((size_t)(p & 0x0FFFFFFFu) << 7)))[lane];
            ACC(p, u);
        }
    }

    const float nv_l = (lane < 8) ? inv_norm[(size_t)lane * N + dst] : 0.f;

    unsigned short* Arow = A + (size_t)dst * 1024 + lane * 2;   // pitch R*128
    {
        float s;
        s = readlane_f(nv_l, 0); *(unsigned*)(Arow + 0*128) = (unsigned)f2bf(ax0*s) | ((unsigned)f2bf(ay0*s) << 16);
        s = readlane_f(nv_l, 1); *(unsigned*)(Arow + 1*128) = (unsigned)f2bf(ax1*s) | ((unsigned)f2bf(ay1*s) << 16);
        s = readlane_f(nv_l, 2); *(unsigned*)(Arow + 2*128) = (unsigned)f2bf(ax2*s) | ((unsigned)f2bf(ay2*s) << 16);
        s = readlane_f(nv_l, 3); *(unsigned*)(Arow + 3*128) = (unsigned)f2bf(ax3*s) | ((unsigned)f2bf(ay3*s) << 16);
        s = readlane_f(nv_l, 4); *(unsigned*)(Arow + 4*128) = (unsigned)f2bf(ax4*s) | ((unsigned)f2bf(ay4*s) << 16);
        s = readlane_f(nv_l, 5); *(unsigned*)(Arow + 5*128) = (unsigned)f2bf(ax5*s) | ((unsigned)f2bf(ay5*s) << 16);
        s = readlane_f(nv_l, 6); *(unsigned*)(Arow + 6*128) = (unsigned)f2bf(ax6*s) | ((unsigned)f2bf(ay6*s) << 16);
        s = readlane_f(nv_l, 7); *(unsigned*)(Arow + 7*128) = (unsigned)f2bf(ax7*s) | ((unsigned)f2bf(ay7*s) << 16);
    }
}

// ---------------------------------------------------------------------------
// 3) bf16 MFMA GEMM: out[M,128] = [A | Xb][M,KT] @ Bt[128,KT]^T (fp32 out)
//    256 threads = 4 waves; 64 rows x 128 cols per block; BK=128.
//    BOTH A and B tiles staged in LDS with coalesced 256B-per-row reads,
//    issued before the barrier (overlap with previous iter's MFMA).
//    Wave w handles rows w*16..w*16+15 x all 128 cols (8 MFMA / ks step).
// ---------------------------------------------------------------------------
template <int KT>
__global__ __launch_bounds__(256) void gemm_kernel(
    const unsigned short* __restrict__ A, const unsigned short* __restrict__ Xb,
    const unsigned short* __restrict__ Bt, float* __restrict__ out, int M)
{
    __shared__ unsigned short Asld[64][136];
    __shared__ unsigned short Bsld[128][136];
    const int tid = threadIdx.x;
    const int wave = tid >> 6;               // 0..3 -> 16-row m-tile
    const int lane = tid & 63;
    const int ln = lane & 15, quad = lane >> 4;
    const int m0 = blockIdx.x * 64;

    // A staging: row = tid>>2 (0..63), k-off = (tid&3)*32 shorts (64B)
    const int arow = tid >> 2, akoff = (tid & 3) * 32;
    // B staging: row = tid>>1 (0..127), k-off = (tid&1)*64 shorts (128B)
    const int brow = tid >> 1, bkoff = (tid & 1) * 64;

    int am = m0 + arow; if (am >= M) am = M - 1;
    const unsigned short* ArowG = A + (size_t)am * (KT - 128) + akoff;
    const unsigned short* XrowG = Xb + (size_t)am * 128 + akoff;
    const unsigned short* BrowG = Bt + (size_t)brow * KT + bkoff;

    f32x4 acc[8] = {};
#pragma unroll
    for (int ko = 0; ko < KT / 128; ++ko) {
        const unsigned short* asrc = (ko < KT / 128 - 1) ? (ArowG + ko * 128) : XrowG;
        const short8 a0 = *(const short8*)(asrc + 0);
        const short8 a1 = *(const short8*)(asrc + 8);
        const short8 a2 = *(const short8*)(asrc + 16);
        const short8 a3 = *(const short8*)(asrc + 24);
        const unsigned short* bsrc = BrowG + ko * 128;
        const short8 b0 = *(const short8*)(bsrc + 0);
        const short8 b1 = *(const short8*)(bsrc + 8);
        const short8 b2 = *(const short8*)(bsrc + 16);
        const short8 b3 = *(const short8*)(bsrc + 24);
        const short8 b4 = *(const short8*)(bsrc + 32);
        const short8 b5 = *(const short8*)(bsrc + 40);
        const short8 b6 = *(const short8*)(bsrc + 48);
        const short8 b7 = *(const short8*)(bsrc + 56);
        __syncthreads();                     // previous iter's reads done
        *(short8*)&Asld[arow][akoff + 0]  = a0;
        *(short8*)&Asld[arow][akoff + 8]  = a1;
        *(short8*)&Asld[arow][akoff + 16] = a2;
        *(short8*)&Asld[arow][akoff + 24] = a3;
        *(short8*)&Bsld[brow][bkoff + 0]  = b0;
        *(short8*)&Bsld[brow][bkoff + 8]  = b1;
        *(short8*)&Bsld[brow][bkoff + 16] = b2;
        *(short8*)&Bsld[brow][bkoff + 24] = b3;
        *(short8*)&Bsld[brow][bkoff + 32] = b4;
        *(short8*)&Bsld[brow][bkoff + 40] = b5;
        *(short8*)&Bsld[brow][bkoff + 48] = b6;
        *(short8*)&Bsld[brow][bkoff + 56] = b7;
        __syncthreads();
#pragma unroll
        for (int ks = 0; ks < 4; ++ks) {
            const short8 a = *(const short8*)&Asld[wave * 16 + ln][ks * 32 + quad * 8];
#pragma unroll
            for (int c = 0; c < 8; ++c) {
                const short8 b = *(const short8*)&Bsld[c * 16 + ln][ks * 32 + quad * 8];
                acc[c] = __builtin_amdgcn_mfma_f32_16x16x32_bf16(a, b, acc[c], 0, 0, 0);
            }
        }
    }
#pragma unroll
    for (int c = 0; c < 8; ++c) {
#pragma unroll
        for (int rg = 0; rg < 4; ++rg) {
            const int row = m0 + wave * 16 + quad * 4 + rg;
            if (row < M)
                out[(size_t)row * 128 + c * 16 + ln] = acc[c][rg];
        }
    }
}

// Generic-K fallback (runtime loop bound), slow but correct
__global__ __launch_bounds__(256) void gemm_kernel_rt(
    const unsigned short* __restrict__ A, const unsigned short* __restrict__ Xb,
    const unsigned short* __restrict__ Bt, float* __restrict__ out,
    int M, int ktot)
{
    const int tid = threadIdx.x;
    const int wave = tid >> 6;
    const int lane = tid & 63;
    const int ln = lane & 15, quad = lane >> 4;
    const int m0 = blockIdx.x * 64 + wave * 16;
    int m = m0 + ln; if (m >= M) m = M - 1;
    const unsigned short* Arow = A + (size_t)m * (ktot - 128) + quad * 8;
    const unsigned short* Xrow = Xb + (size_t)m * 128 + quad * 8;
    const unsigned short* Bbase = Bt + (size_t)ln * ktot + quad * 8;

    f32x4 acc[8] = {};
    for (int kb = 0; kb < (ktot >> 5); ++kb) {
        const int k0 = kb << 5;
        const unsigned short* asrc = (k0 < ktot - 128) ? (Arow + k0) : (Xrow + (k0 - (ktot - 128)));
        const short8 a = *(const short8*)asrc;
#pragma unroll
        for (int c = 0; c < 8; ++c) {
            const short8 b = *(const short8*)(Bbase + (size_t)c * 16 * ktot + k0);
            acc[c] = __builtin_amdgcn_mfma_f32_16x16x32_bf16(a, b, acc[c], 0, 0, 0);
        }
    }
#pragma unroll
    for (int c = 0; c < 8; ++c) {
#pragma unroll
        for (int rg = 0; rg < 4; ++rg) {
            const int row = m0 + quad * 4 + rg;
            if (row < M) out[(size_t)row * 128 + c * 16 + ln] = acc[c][rg];
        }
    }
}

// ---------------------------------------------------------------------------
extern "C" void kernel_launch(void* const* d_in, const int* in_sizes, int n_in,
                              void* d_out, int out_size, void* d_ws, size_t ws_size,
                              hipStream_t stream) {
    const float* X        = (const float*)d_in[0];
    const float* W        = (const float*)d_in[1];
    const float* W0       = (const float*)d_in[2];
    const float* inv_norm = (const float*)d_in[3];
    const int*   esrc     = (const int*)d_in[4];
    const int*   edst     = (const int*)d_in[5];
    const int*   erel     = (const int*)d_in[6];
    float* out = (float*)d_out;

    const int N  = in_sizes[0] / 128;     // 50000
    const int E  = in_sizes[4];           // 800000
    const int R  = in_sizes[3] / N;       // 8
    const int ktot = (R + 1) * 128;       // 1152

    char* ws = (char*)d_ws;
    size_t off = 0;
    auto alloc = [&](size_t bytes) -> char* {
        char* p = ws + off; off = (off + bytes + 255) & ~(size_t)255; return p;
    };
    unsigned short* A         = (unsigned short*)alloc((size_t)N * R * 128 * 2); // 102.4 MB
    unsigned short* Xb        = (unsigned short*)alloc((size_t)N * 128 * 2);     // 12.8 MB
    unsigned short* Bt        = (unsigned short*)alloc((size_t)128 * ktot * 2);  // 0.3 MB
    int*            counts    = (int*)alloc((size_t)N * 4);                      // 0.2 MB
    int*            offsets   = (int*)alloc((size_t)N * 4);                      // 0.2 MB
    int*            blockSums = (int*)alloc(1024 * 4);
    unsigned*       sorted    = (unsigned*)alloc((size_t)E * 4);                 // 3.2 MB
    (void)ws_size;

    // cooperative prep: 256 blocks x 1024 threads (2 blocks/CU co-resident max;
    // 256 blocks <= 256 CUs -> safely co-resident for grid.sync)
    {
        const float *Xp = X, *Wp = W, *W0p = W0;
        const int *esp = esrc, *edp = edst, *erp = erel;
        unsigned short *Xbp = Xb, *Btp = Bt;
        int *cp = counts, *op = offsets, *bsp = blockSums;
        unsigned *sp = sorted;
        int Nv = N, Ev = E, Rv = R;
        void* args[] = { &Xp, &Wp, &W0p, &esp, &edp, &erp, &Xbp, &Btp,
                         &cp, &op, &bsp, &sp, &Nv, &Ev, &Rv };
        hipLaunchCooperativeKernel((const void*)prep_kernel,
                                   dim3(256), dim3(1024), args, 0, stream);
    }

    aggregate_kernel<<<(N + 3) / 4, 256, 0, stream>>>(Xb, inv_norm, sorted, counts, offsets, A, N);
    if (ktot == 1152)
        gemm_kernel<1152><<<(N + 63) / 64, 256, 0, stream>>>(A, Xb, Bt, out, N);
    else
        gemm_kernel_rt<<<(N + 63) / 64, 256, 0, stream>>>(A, Xb, Bt, out, N, ktot);
}

// Round 11
// 286.424 us; speedup vs baseline: 1.4195x; 1.4195x over previous
//
#include <hip/hip_runtime.h>

typedef __attribute__((ext_vector_type(8))) short short8;
typedef __attribute__((ext_vector_type(4))) float f32x4;

__device__ __forceinline__ unsigned short f2bf(float f) {
    unsigned u = __float_as_uint(f);
    u += 0x7FFF + ((u >> 16) & 1);          // round-to-nearest-even
    return (unsigned short)(u >> 16);
}

__device__ __forceinline__ float readlane_f(float v, int l) {
    return __int_as_float(__builtin_amdgcn_readlane(__float_as_int(v), l));
}

__device__ __forceinline__ float bflo(unsigned u) { return __uint_as_float(u << 16); }
__device__ __forceinline__ float bfhi(unsigned u) { return __uint_as_float(u & 0xFFFF0000u); }

// ---------------------------------------------------------------------------
// 1) Histogram of edges over dst (N bins)
// ---------------------------------------------------------------------------
__global__ __launch_bounds__(256) void hist_kernel(
    const int* __restrict__ edst, int* __restrict__ counts, int E)
{
    int i = blockIdx.x * 256 + threadIdx.x;
    const int stride = gridDim.x * 256;
    for (; i < E; i += stride)
        atomicAdd(&counts[edst[i]], 1);
}

// ---------------------------------------------------------------------------
// 2) Exclusive prefix scan over counts[NB] (3 wide kernels, 1024 items/block)
// ---------------------------------------------------------------------------
__global__ __launch_bounds__(256) void scan1_kernel(
    const int* __restrict__ counts, int* __restrict__ blockSums, int NB)
{
    __shared__ int sd[256];
    const int t = threadIdx.x;
    const int base = blockIdx.x * 1024 + t * 4;
    int s = 0;
#pragma unroll
    for (int i = 0; i < 4; ++i) { int idx = base + i; if (idx < NB) s += counts[idx]; }
    sd[t] = s; __syncthreads();
    for (int off = 128; off > 0; off >>= 1) {
        if (t < off) sd[t] += sd[t + off];
        __syncthreads();
    }
    if (t == 0) blockSums[blockIdx.x] = sd[0];
}

__global__ __launch_bounds__(512) void scan2_kernel(int* blockSums, int nb)
{
    __shared__ int sd[512];
    const int t = threadIdx.x;
    const int v = (t < nb) ? blockSums[t] : 0;
    sd[t] = v; __syncthreads();
    for (int off = 1; off < 512; off <<= 1) {
        int x = (t >= off) ? sd[t - off] : 0;
        __syncthreads();
        sd[t] += x;
        __syncthreads();
    }
    if (t < nb) blockSums[t] = sd[t] - v;   // exclusive
}

__global__ __launch_bounds__(256) void scan3_kernel(
    const int* __restrict__ counts, const int* __restrict__ blockSums,
    int* __restrict__ offsets, int NB)
{
    __shared__ int sd[256];
    const int t = threadIdx.x;
    const int base = blockIdx.x * 1024 + t * 4;
    int c[4]; int s = 0;
#pragma unroll
    for (int i = 0; i < 4; ++i) { int idx = base + i; c[i] = (idx < NB) ? counts[idx] : 0; s += c[i]; }
    sd[t] = s; __syncthreads();
    for (int off = 1; off < 256; off <<= 1) {
        int x = (t >= off) ? sd[t - off] : 0;
        __syncthreads();
        sd[t] += x;
        __syncthreads();
    }
    int run = sd[t] - s + blockSums[blockIdx.x];
#pragma unroll
    for (int i = 0; i < 4; ++i) { int idx = base + i; if (idx < NB) offsets[idx] = run; run += c[i]; }
}

// ---------------------------------------------------------------------------
// 3) Scatter payload (rel<<28)|src into dst-sorted order.
//    Destroys offsets: afterwards offsets[dst] == end of bucket.
// ---------------------------------------------------------------------------
__global__ __launch_bounds__(256) void scatter_fill_kernel(
    const int* __restrict__ esrc, const int* __restrict__ edst,
    const int* __restrict__ erel, int* __restrict__ offsets,
    unsigned* __restrict__ sorted, int E)
{
    int i = blockIdx.x * 256 + threadIdx.x;
    const int stride = gridDim.x * 256;
    for (; i < E; i += stride) {
        const int pos = atomicAdd(&offsets[edst[i]], 1);
        sorted[pos] = (unsigned)esrc[i] | ((unsigned)erel[i] << 28);
    }
}

// ---------------------------------------------------------------------------
// 4) Cast X -> Xb (bf16) and [W;W0]^T -> Bt (bf16). Wide one-shot grid.
// ---------------------------------------------------------------------------
__global__ __launch_bounds__(256) void cast_kernel(
    const float* __restrict__ X, const float* __restrict__ W,
    const float* __restrict__ W0, unsigned short* __restrict__ Xb,
    unsigned short* __restrict__ Bt, int M, int R)
{
    const int ktot = (R + 1) * 128;
    const int nx = M * 32;                 // float4 chunks of X
    const int idx = blockIdx.x * 256 + threadIdx.x;
    if (idx < nx) {
        const float4 v = ((const float4*)X)[idx];
        uint2 p;
        p.x = (unsigned)f2bf(v.x) | ((unsigned)f2bf(v.y) << 16);
        p.y = (unsigned)f2bf(v.z) | ((unsigned)f2bf(v.w) << 16);
        *(uint2*)(Xb + (size_t)idx * 4) = p;
    } else if (idx < nx + 128 * ktot) {
        const int e = idx - nx;
        const int n = e / ktot;
        const int k = e - n * ktot;
        const float v = (k < R * 128) ? W[(size_t)k * 128 + n]
                                      : W0[(size_t)(k - R * 128) * 128 + n];
        Bt[(size_t)n * ktot + k] = f2bf(v);
    }
}

// ---------------------------------------------------------------------------
// 5) dst-major aggregate, one wave per dst (unchanged from round 9/7 form).
// ---------------------------------------------------------------------------
#define ACC(P, U) switch ((P) >> 28) {                                   \
        case 0: ax0 += bflo(U); ay0 += bfhi(U); break;                   \
        case 1: ax1 += bflo(U); ay1 += bfhi(U); break;                   \
        case 2: ax2 += bflo(U); ay2 += bfhi(U); break;                   \
        case 3: ax3 += bflo(U); ay3 += bfhi(U); break;                   \
        case 4: ax4 += bflo(U); ay4 += bfhi(U); break;                   \
        case 5: ax5 += bflo(U); ay5 += bfhi(U); break;                   \
        case 6: ax6 += bflo(U); ay6 += bfhi(U); break;                   \
        default: ax7 += bflo(U); ay7 += bfhi(U); break; }

__global__ __launch_bounds__(256) void aggregate_kernel(
    const unsigned short* __restrict__ Xb, const float* __restrict__ inv_norm,
    const unsigned* __restrict__ sorted, const int* __restrict__ counts,
    const int* __restrict__ bucket_end, unsigned short* __restrict__ A,
    int N)
{
    const int dst = (int)((blockIdx.x * blockDim.x + threadIdx.x) >> 6);
    if (dst >= N) return;
    const int lane = threadIdx.x & 63;

    const int end = bucket_end[dst];
    const int start = end - counts[dst];

    float ax0=0,ay0=0, ax1=0,ay1=0, ax2=0,ay2=0, ax3=0,ay3=0;
    float ax4=0,ay4=0, ax5=0,ay5=0, ax6=0,ay6=0, ax7=0,ay7=0;

    for (int cb = start; cb < end; cb += 64) {
        const int take = min(64, end - cb);
        unsigned batch = 0;
        if (cb + lane < end) batch = sorted[cb + lane];
        int j = 0;
        for (; j + 8 <= take; j += 8) {
            unsigned p[8], u[8];
#pragma unroll
            for (int q = 0; q < 8; ++q)
                p[q] = (unsigned)__builtin_amdgcn_readlane((int)batch, j + q);
#pragma unroll
            for (int q = 0; q < 8; ++q)
                u[q] = ((const unsigned*)(Xb + ((size_t)(p[q] & 0x0FFFFFFFu) << 7)))[lane];
            ACC(p[0], u[0]); ACC(p[1], u[1]); ACC(p[2], u[2]); ACC(p[3], u[3]);
            ACC(p[4], u[4]); ACC(p[5], u[5]); ACC(p[6], u[6]); ACC(p[7], u[7]);
        }
        for (; j + 4 <= take; j += 4) {
            const unsigned p0 = (unsigned)__builtin_amdgcn_readlane((int)batch, j);
            const unsigned p1 = (unsigned)__builtin_amdgcn_readlane((int)batch, j + 1);
            const unsigned p2 = (unsigned)__builtin_amdgcn_readlane((int)batch, j + 2);
            const unsigned p3 = (unsigned)__builtin_amdgcn_readlane((int)batch, j + 3);
            const unsigned u0 = ((const unsigned*)(Xb + ((size_t)(p0 & 0x0FFFFFFFu) << 7)))[lane];
            const unsigned u1 = ((const unsigned*)(Xb + ((size_t)(p1 & 0x0FFFFFFFu) << 7)))[lane];
            const unsigned u2 = ((const unsigned*)(Xb + ((size_t)(p2 & 0x0FFFFFFFu) << 7)))[lane];
            const unsigned u3 = ((const unsigned*)(Xb + ((size_t)(p3 & 0x0FFFFFFFu) << 7)))[lane];
            ACC(p0, u0); ACC(p1, u1); ACC(p2, u2); ACC(p3, u3);
        }
        for (; j < take; ++j) {
            const unsigned p = (unsigned)__builtin_amdgcn_readlane((int)batch, j);
            const unsigned u = ((const unsigned*)(Xb + ((size_t)(p & 0x0FFFFFFFu) << 7)))[lane];
            ACC(p, u);
        }
    }

    const float nv_l = (lane < 8) ? inv_norm[(size_t)lane * N + dst] : 0.f;

    unsigned short* Arow = A + (size_t)dst * 1024 + lane * 2;   // pitch R*128
    {
        float s;
        s = readlane_f(nv_l, 0); *(unsigned*)(Arow + 0*128) = (unsigned)f2bf(ax0*s) | ((unsigned)f2bf(ay0*s) << 16);
        s = readlane_f(nv_l, 1); *(unsigned*)(Arow + 1*128) = (unsigned)f2bf(ax1*s) | ((unsigned)f2bf(ay1*s) << 16);
        s = readlane_f(nv_l, 2); *(unsigned*)(Arow + 2*128) = (unsigned)f2bf(ax2*s) | ((unsigned)f2bf(ay2*s) << 16);
        s = readlane_f(nv_l, 3); *(unsigned*)(Arow + 3*128) = (unsigned)f2bf(ax3*s) | ((unsigned)f2bf(ay3*s) << 16);
        s = readlane_f(nv_l, 4); *(unsigned*)(Arow + 4*128) = (unsigned)f2bf(ax4*s) | ((unsigned)f2bf(ay4*s) << 16);
        s = readlane_f(nv_l, 5); *(unsigned*)(Arow + 5*128) = (unsigned)f2bf(ax5*s) | ((unsigned)f2bf(ay5*s) << 16);
        s = readlane_f(nv_l, 6); *(unsigned*)(Arow + 6*128) = (unsigned)f2bf(ax6*s) | ((unsigned)f2bf(ay6*s) << 16);
        s = readlane_f(nv_l, 7); *(unsigned*)(Arow + 7*128) = (unsigned)f2bf(ax7*s) | ((unsigned)f2bf(ay7*s) << 16);
    }
}

// ---------------------------------------------------------------------------
// 6) bf16 MFMA GEMM: out[M,128] = [A | Xb][M,KT] @ Bt[128,KT]^T (fp32 out)
//    256 threads = 4 waves; 64 rows x 128 cols; BK=128; BOTH tiles staged
//    in LDS via coalesced 256B-per-row reads issued before the barrier.
//    XOR-swizzled chunk layout (chunk' = chunk ^ (row&7), 16B chunks, no
//    padding): every staging write and fragment read spreads 8 lanes per
//    bank-quad = LDS minimum, conflict-free.
// ---------------------------------------------------------------------------
template <int KT>
__global__ __launch_bounds__(256) void gemm_kernel(
    const unsigned short* __restrict__ A, const unsigned short* __restrict__ Xb,
    const unsigned short* __restrict__ Bt, float* __restrict__ out, int M)
{
    __shared__ unsigned short Asw[64 * 128];    // 16.4 KB
    __shared__ unsigned short Bsw[128 * 128];   // 32.8 KB
    const int tid = threadIdx.x;
    const int wave = tid >> 6;               // 0..3 -> 16-row m-tile
    const int lane = tid & 63;
    const int ln = lane & 15, quad = lane >> 4;
    const int m0 = blockIdx.x * 64;

    // A staging: row ar = tid>>2, 4 chunks of 8 shorts at group aq = tid&3
    const int ar = tid >> 2, aq = tid & 3;
    int am = m0 + ar; if (am >= M) am = M - 1;
    const unsigned short* ArowG = A + (size_t)am * (KT - 128) + aq * 32;
    const unsigned short* XrowG = Xb + (size_t)am * 128 + aq * 32;
    // B staging: row br = tid>>1, 8 chunks at half bq = tid&1
    const int br = tid >> 1, bq = tid & 1;
    const unsigned short* BrowG = Bt + (size_t)br * KT + bq * 64;

    f32x4 acc[8] = {};
#pragma unroll
    for (int ko = 0; ko < KT / 128; ++ko) {
        const unsigned short* asrc = (ko < KT / 128 - 1) ? (ArowG + ko * 128) : XrowG;
        short8 av[4];
#pragma unroll
        for (int i = 0; i < 4; ++i) av[i] = *(const short8*)(asrc + i * 8);
        short8 bv[8];
#pragma unroll
        for (int i = 0; i < 8; ++i) bv[i] = *(const short8*)(BrowG + ko * 128 + i * 8);
        __syncthreads();                         // prev iter's LDS reads done
#pragma unroll
        for (int i = 0; i < 4; ++i) {
            const int c = aq * 4 + i;
            *(short8*)&Asw[ar * 128 + (((c ^ (ar & 7)) & 15) << 3)] = av[i];
        }
#pragma unroll
        for (int i = 0; i < 8; ++i) {
            const int c = bq * 8 + i;
            *(short8*)&Bsw[br * 128 + (((c ^ (br & 7)) & 15) << 3)] = bv[i];
        }
        __syncthreads();
#pragma unroll
        for (int ks = 0; ks < 4; ++ks) {
            const int ca = ((ks * 4 + quad) ^ (ln & 7)) & 15;
            const short8 a = *(const short8*)&Asw[(wave * 16 + ln) * 128 + (ca << 3)];
#pragma unroll
            for (int c = 0; c < 8; ++c) {
                const int rb = c * 16 + ln;                 // rb&7 == ln&7
                const int cb = ((ks * 4 + quad) ^ (ln & 7)) & 15;
                const short8 b = *(const short8*)&Bsw[rb * 128 + (cb << 3)];
                acc[c] = __builtin_amdgcn_mfma_f32_16x16x32_bf16(a, b, acc[c], 0, 0, 0);
            }
        }
    }
#pragma unroll
    for (int c = 0; c < 8; ++c) {
#pragma unroll
        for (int rg = 0; rg < 4; ++rg) {
            const int row = m0 + wave * 16 + quad * 4 + rg;
            if (row < M)
                out[(size_t)row * 128 + c * 16 + ln] = acc[c][rg];
        }
    }
}

// Generic-K fallback (runtime loop bound), slow but correct
__global__ __launch_bounds__(256) void gemm_kernel_rt(
    const unsigned short* __restrict__ A, const unsigned short* __restrict__ Xb,
    const unsigned short* __restrict__ Bt, float* __restrict__ out,
    int M, int ktot)
{
    const int tid = threadIdx.x;
    const int wave = tid >> 6;
    const int lane = tid & 63;
    const int ln = lane & 15, quad = lane >> 4;
    const int m0 = blockIdx.x * 64 + wave * 16;
    int m = m0 + ln; if (m >= M) m = M - 1;
    const unsigned short* Arow = A + (size_t)m * (ktot - 128) + quad * 8;
    const unsigned short* Xrow = Xb + (size_t)m * 128 + quad * 8;
    const unsigned short* Bbase = Bt + (size_t)ln * ktot + quad * 8;

    f32x4 acc[8] = {};
    for (int kb = 0; kb < (ktot >> 5); ++kb) {
        const int k0 = kb << 5;
        const unsigned short* asrc = (k0 < ktot - 128) ? (Arow + k0) : (Xrow + (k0 - (ktot - 128)));
        const short8 a = *(const short8*)asrc;
#pragma unroll
        for (int c = 0; c < 8; ++c) {
            const short8 b = *(const short8*)(Bbase + (size_t)c * 16 * ktot + k0);
            acc[c] = __builtin_amdgcn_mfma_f32_16x16x32_bf16(a, b, acc[c], 0, 0, 0);
        }
    }
#pragma unroll
    for (int c = 0; c < 8; ++c) {
#pragma unroll
        for (int rg = 0; rg < 4; ++rg) {
            const int row = m0 + quad * 4 + rg;
            if (row < M) out[(size_t)row * 128 + c * 16 + ln] = acc[c][rg];
        }
    }
}

// ---------------------------------------------------------------------------
extern "C" void kernel_launch(void* const* d_in, const int* in_sizes, int n_in,
                              void* d_out, int out_size, void* d_ws, size_t ws_size,
                              hipStream_t stream) {
    const float* X        = (const float*)d_in[0];
    const float* W        = (const float*)d_in[1];
    const float* W0       = (const float*)d_in[2];
    const float* inv_norm = (const float*)d_in[3];
    const int*   esrc     = (const int*)d_in[4];
    const int*   edst     = (const int*)d_in[5];
    const int*   erel     = (const int*)d_in[6];
    float* out = (float*)d_out;

    const int N  = in_sizes[0] / 128;     // 50000
    const int E  = in_sizes[4];           // 800000
    const int R  = in_sizes[3] / N;       // 8
    const int ktot = (R + 1) * 128;       // 1152

    char* ws = (char*)d_ws;
    size_t off = 0;
    auto alloc = [&](size_t bytes) -> char* {
        char* p = ws + off; off = (off + bytes + 255) & ~(size_t)255; return p;
    };
    unsigned short* A         = (unsigned short*)alloc((size_t)N * R * 128 * 2); // 102.4 MB
    unsigned short* Xb        = (unsigned short*)alloc((size_t)N * 128 * 2);     // 12.8 MB
    unsigned short* Bt        = (unsigned short*)alloc((size_t)128 * ktot * 2);  // 0.3 MB
    int*            counts    = (int*)alloc((size_t)N * 4);                      // 0.2 MB
    int*            offsets   = (int*)alloc((size_t)N * 4);                      // 0.2 MB
    int*            blockSums = (int*)alloc(512 * 4);
    unsigned*       sorted    = (unsigned*)alloc((size_t)E * 4);                 // 3.2 MB
    (void)ws_size;

    const int nScanBlocks = (N + 1023) / 1024;   // 49 (<=512)

    hipMemsetAsync(counts, 0, (size_t)N * 4, stream);
    hist_kernel<<<1024, 256, 0, stream>>>(edst, counts, E);
    scan1_kernel<<<nScanBlocks, 256, 0, stream>>>(counts, blockSums, N);
    scan2_kernel<<<1, 512, 0, stream>>>(blockSums, nScanBlocks);
    scan3_kernel<<<nScanBlocks, 256, 0, stream>>>(counts, blockSums, offsets, N);
    scatter_fill_kernel<<<1024, 256, 0, stream>>>(esrc, edst, erel, offsets, sorted, E);
    cast_kernel<<<(N * 32 + 128 * ktot + 255) / 256, 256, 0, stream>>>(X, W, W0, Xb, Bt, N, R);
    aggregate_kernel<<<(N + 3) / 4, 256, 0, stream>>>(Xb, inv_norm, sorted, counts, offsets, A, N);
    if (ktot == 1152)
        gemm_kernel<1152><<<(N + 63) / 64, 256, 0, stream>>>(A, Xb, Bt, out, N);
    else
        gemm_kernel_rt<<<(N + 63) / 64, 256, 0, stream>>>(A, Xb, Bt, out, N, ktot);
}

// Round 12
// 275.451 us; speedup vs baseline: 1.4760x; 1.0398x over previous
//
#include <hip/hip_runtime.h>

typedef __attribute__((ext_vector_type(8))) short short8;
typedef __attribute__((ext_vector_type(4))) float f32x4;

__device__ __forceinline__ unsigned short f2bf(float f) {
    unsigned u = __float_as_uint(f);
    u += 0x7FFF + ((u >> 16) & 1);          // round-to-nearest-even
    return (unsigned short)(u >> 16);
}

__device__ __forceinline__ float readlane_f(float v, int l) {
    return __int_as_float(__builtin_amdgcn_readlane(__float_as_int(v), l));
}

__device__ __forceinline__ float bflo(unsigned u) { return __uint_as_float(u << 16); }
__device__ __forceinline__ float bfhi(unsigned u) { return __uint_as_float(u & 0xFFFF0000u); }

// ---------------------------------------------------------------------------
// 1) Histogram over key = dst*8 + rel (8N bins — spreads atomic contention
//    to ~2 edges/bin; 50k-bin version serialized 16-deep and was 2x slower)
// ---------------------------------------------------------------------------
__global__ __launch_bounds__(256) void hist_kernel(
    const int* __restrict__ edst, const int* __restrict__ erel,
    int* __restrict__ counts, int E)
{
    int i = blockIdx.x * 256 + threadIdx.x;
    const int stride = gridDim.x * 256;
    for (; i < E; i += stride)
        atomicAdd(&counts[edst[i] * 8 + erel[i]], 1);
}

// ---------------------------------------------------------------------------
// 2) Exclusive prefix scan over counts[KB] (3 wide kernels, 1024 items/block)
// ---------------------------------------------------------------------------
__global__ __launch_bounds__(256) void scan1_kernel(
    const int* __restrict__ counts, int* __restrict__ blockSums, int KB)
{
    __shared__ int sd[256];
    const int t = threadIdx.x;
    const int base = blockIdx.x * 1024 + t * 4;
    int s = 0;
#pragma unroll
    for (int i = 0; i < 4; ++i) { int idx = base + i; if (idx < KB) s += counts[idx]; }
    sd[t] = s; __syncthreads();
    for (int off = 128; off > 0; off >>= 1) {
        if (t < off) sd[t] += sd[t + off];
        __syncthreads();
    }
    if (t == 0) blockSums[blockIdx.x] = sd[0];
}

__global__ __launch_bounds__(512) void scan2_kernel(int* blockSums, int nb)
{
    __shared__ int sd[512];
    const int t = threadIdx.x;
    const int v = (t < nb) ? blockSums[t] : 0;
    sd[t] = v; __syncthreads();
    for (int off = 1; off < 512; off <<= 1) {
        int x = (t >= off) ? sd[t - off] : 0;
        __syncthreads();
        sd[t] += x;
        __syncthreads();
    }
    if (t < nb) blockSums[t] = sd[t] - v;   // exclusive
}

__global__ __launch_bounds__(256) void scan3_kernel(
    const int* __restrict__ counts, const int* __restrict__ blockSums,
    int* __restrict__ offsets, int* __restrict__ starts, int KB)
{
    __shared__ int sd[256];
    const int t = threadIdx.x;
    const int base = blockIdx.x * 1024 + t * 4;
    int c[4]; int s = 0;
#pragma unroll
    for (int i = 0; i < 4; ++i) { int idx = base + i; c[i] = (idx < KB) ? counts[idx] : 0; s += c[i]; }
    sd[t] = s; __syncthreads();
    for (int off = 1; off < 256; off <<= 1) {
        int x = (t >= off) ? sd[t - off] : 0;
        __syncthreads();
        sd[t] += x;
        __syncthreads();
    }
    int run = sd[t] - s + blockSums[blockIdx.x];
#pragma unroll
    for (int i = 0; i < 4; ++i) {
        int idx = base + i;
        if (idx < KB) { offsets[idx] = run; starts[idx] = run; }
        run += c[i];
    }
}

// ---------------------------------------------------------------------------
// 3) Scatter payload (rel<<28)|src into (dst,rel)-sorted order.
//    Destroys offsets; `starts` keeps the pristine bucket bases.
// ---------------------------------------------------------------------------
__global__ __launch_bounds__(256) void scatter_fill_kernel(
    const int* __restrict__ esrc, const int* __restrict__ edst,
    const int* __restrict__ erel, int* __restrict__ offsets,
    unsigned* __restrict__ sorted, int E)
{
    int i = blockIdx.x * 256 + threadIdx.x;
    const int stride = gridDim.x * 256;
    for (; i < E; i += stride) {
        const int r = erel[i];
        const int pos = atomicAdd(&offsets[edst[i] * 8 + r], 1);
        sorted[pos] = (unsigned)esrc[i] | ((unsigned)r << 28);
    }
}

// ---------------------------------------------------------------------------
// 4) Cast X -> Xb (bf16) and [W;W0]^T -> Bt (bf16). Wide one-shot grid.
// ---------------------------------------------------------------------------
__global__ __launch_bounds__(256) void cast_kernel(
    const float* __restrict__ X, const float* __restrict__ W,
    const float* __restrict__ W0, unsigned short* __restrict__ Xb,
    unsigned short* __restrict__ Bt, int M, int R)
{
    const int ktot = (R + 1) * 128;
    const int nx = M * 32;                 // float4 chunks of X
    const int idx = blockIdx.x * 256 + threadIdx.x;
    if (idx < nx) {
        const float4 v = ((const float4*)X)[idx];
        uint2 p;
        p.x = (unsigned)f2bf(v.x) | ((unsigned)f2bf(v.y) << 16);
        p.y = (unsigned)f2bf(v.z) | ((unsigned)f2bf(v.w) << 16);
        *(uint2*)(Xb + (size_t)idx * 4) = p;
    } else if (idx < nx + 128 * ktot) {
        const int e = idx - nx;
        const int n = e / ktot;
        const int k = e - n * ktot;
        const float v = (k < R * 128) ? W[(size_t)k * 128 + n]
                                      : W0[(size_t)(k - R * 128) * 128 + n];
        Bt[(size_t)n * ktot + k] = f2bf(v);
    }
}

// ---------------------------------------------------------------------------
// 5) dst-major aggregate, one wave per dst. Bucket bounds from preserved
//    starts[]: start = starts[dst*8], end = starts[(dst+1)*8] (E for last).
//    switch(rel) on readlane SGPR -> named-VGPR accumulators, no LDS.
// ---------------------------------------------------------------------------
#define ACC(P, U) switch ((P) >> 28) {                                   \
        case 0: ax0 += bflo(U); ay0 += bfhi(U); break;                   \
        case 1: ax1 += bflo(U); ay1 += bfhi(U); break;                   \
        case 2: ax2 += bflo(U); ay2 += bfhi(U); break;                   \
        case 3: ax3 += bflo(U); ay3 += bfhi(U); break;                   \
        case 4: ax4 += bflo(U); ay4 += bfhi(U); break;                   \
        case 5: ax5 += bflo(U); ay5 += bfhi(U); break;                   \
        case 6: ax6 += bflo(U); ay6 += bfhi(U); break;                   \
        default: ax7 += bflo(U); ay7 += bfhi(U); break; }

__global__ __launch_bounds__(256) void aggregate_kernel(
    const unsigned short* __restrict__ Xb, const float* __restrict__ inv_norm,
    const unsigned* __restrict__ sorted, const int* __restrict__ starts,
    unsigned short* __restrict__ A, int N, int E)
{
    const int dst = (int)((blockIdx.x * blockDim.x + threadIdx.x) >> 6);
    if (dst >= N) return;
    const int lane = threadIdx.x & 63;

    const int start = starts[dst * 8];
    const int end = (dst + 1 < N) ? starts[dst * 8 + 8] : E;

    float ax0=0,ay0=0, ax1=0,ay1=0, ax2=0,ay2=0, ax3=0,ay3=0;
    float ax4=0,ay4=0, ax5=0,ay5=0, ax6=0,ay6=0, ax7=0,ay7=0;

    for (int cb = start; cb < end; cb += 64) {
        const int take = min(64, end - cb);
        unsigned batch = 0;
        if (cb + lane < end) batch = sorted[cb + lane];
        int j = 0;
        for (; j + 8 <= take; j += 8) {
            unsigned p[8], u[8];
#pragma unroll
            for (int q = 0; q < 8; ++q)
                p[q] = (unsigned)__builtin_amdgcn_readlane((int)batch, j + q);
#pragma unroll
            for (int q = 0; q < 8; ++q)
                u[q] = ((const unsigned*)(Xb + ((size_t)(p[q] & 0x0FFFFFFFu) << 7)))[lane];
            ACC(p[0], u[0]); ACC(p[1], u[1]); ACC(p[2], u[2]); ACC(p[3], u[3]);
            ACC(p[4], u[4]); ACC(p[5], u[5]); ACC(p[6], u[6]); ACC(p[7], u[7]);
        }
        for (; j + 4 <= take; j += 4) {
            const unsigned p0 = (unsigned)__builtin_amdgcn_readlane((int)batch, j);
            const unsigned p1 = (unsigned)__builtin_amdgcn_readlane((int)batch, j + 1);
            const unsigned p2 = (unsigned)__builtin_amdgcn_readlane((int)batch, j + 2);
            const unsigned p3 = (unsigned)__builtin_amdgcn_readlane((int)batch, j + 3);
            const unsigned u0 = ((const unsigned*)(Xb + ((size_t)(p0 & 0x0FFFFFFFu) << 7)))[lane];
            const unsigned u1 = ((const unsigned*)(Xb + ((size_t)(p1 & 0x0FFFFFFFu) << 7)))[lane];
            const unsigned u2 = ((const unsigned*)(Xb + ((size_t)(p2 & 0x0FFFFFFFu) << 7)))[lane];
            const unsigned u3 = ((const unsigned*)(Xb + ((size_t)(p3 & 0x0FFFFFFFu) << 7)))[lane];
            ACC(p0, u0); ACC(p1, u1); ACC(p2, u2); ACC(p3, u3);
        }
        for (; j < take; ++j) {
            const unsigned p = (unsigned)__builtin_amdgcn_readlane((int)batch, j);
            const unsigned u = ((const unsigned*)(Xb + ((size_t)(p & 0x0FFFFFFFu) << 7)))[lane];
            ACC(p, u);
        }
    }

    const float nv_l = (lane < 8) ? inv_norm[(size_t)lane * N + dst] : 0.f;

    unsigned short* Arow = A + (size_t)dst * 1024 + lane * 2;   // pitch R*128
    {
        float s;
        s = readlane_f(nv_l, 0); *(unsigned*)(Arow + 0*128) = (unsigned)f2bf(ax0*s) | ((unsigned)f2bf(ay0*s) << 16);
        s = readlane_f(nv_l, 1); *(unsigned*)(Arow + 1*128) = (unsigned)f2bf(ax1*s) | ((unsigned)f2bf(ay1*s) << 16);
        s = readlane_f(nv_l, 2); *(unsigned*)(Arow + 2*128) = (unsigned)f2bf(ax2*s) | ((unsigned)f2bf(ay2*s) << 16);
        s = readlane_f(nv_l, 3); *(unsigned*)(Arow + 3*128) = (unsigned)f2bf(ax3*s) | ((unsigned)f2bf(ay3*s) << 16);
        s = readlane_f(nv_l, 4); *(unsigned*)(Arow + 4*128) = (unsigned)f2bf(ax4*s) | ((unsigned)f2bf(ay4*s) << 16);
        s = readlane_f(nv_l, 5); *(unsigned*)(Arow + 5*128) = (unsigned)f2bf(ax5*s) | ((unsigned)f2bf(ay5*s) << 16);
        s = readlane_f(nv_l, 6); *(unsigned*)(Arow + 6*128) = (unsigned)f2bf(ax6*s) | ((unsigned)f2bf(ay6*s) << 16);
        s = readlane_f(nv_l, 7); *(unsigned*)(Arow + 7*128) = (unsigned)f2bf(ax7*s) | ((unsigned)f2bf(ay7*s) << 16);
    }
}

// ---------------------------------------------------------------------------
// 6) bf16 MFMA GEMM: out[M,128] = [A | Xb][M,KT] @ Bt[128,KT]^T (fp32 out)
//    256 threads = 4 waves; 64 rows x 128 cols; BK=128; both tiles staged
//    in LDS via coalesced 256B-per-row reads; XOR-swizzled chunk layout
//    (conflict-free). Unchanged from round 11 (verified win).
// ---------------------------------------------------------------------------
template <int KT>
__global__ __launch_bounds__(256) void gemm_kernel(
    const unsigned short* __restrict__ A, const unsigned short* __restrict__ Xb,
    const unsigned short* __restrict__ Bt, float* __restrict__ out, int M)
{
    __shared__ unsigned short Asw[64 * 128];    // 16.4 KB
    __shared__ unsigned short Bsw[128 * 128];   // 32.8 KB
    const int tid = threadIdx.x;
    const int wave = tid >> 6;               // 0..3 -> 16-row m-tile
    const int lane = tid & 63;
    const int ln = lane & 15, quad = lane >> 4;
    const int m0 = blockIdx.x * 64;

    const int ar = tid >> 2, aq = tid & 3;
    int am = m0 + ar; if (am >= M) am = M - 1;
    const unsigned short* ArowG = A + (size_t)am * (KT - 128) + aq * 32;
    const unsigned short* XrowG = Xb + (size_t)am * 128 + aq * 32;
    const int br = tid >> 1, bq = tid & 1;
    const unsigned short* BrowG = Bt + (size_t)br * KT + bq * 64;

    f32x4 acc[8] = {};
#pragma unroll
    for (int ko = 0; ko < KT / 128; ++ko) {
        const unsigned short* asrc = (ko < KT / 128 - 1) ? (ArowG + ko * 128) : XrowG;
        short8 av[4];
#pragma unroll
        for (int i = 0; i < 4; ++i) av[i] = *(const short8*)(asrc + i * 8);
        short8 bv[8];
#pragma unroll
        for (int i = 0; i < 8; ++i) bv[i] = *(const short8*)(BrowG + ko * 128 + i * 8);
        __syncthreads();                         // prev iter's LDS reads done
#pragma unroll
        for (int i = 0; i < 4; ++i) {
            const int c = aq * 4 + i;
            *(short8*)&Asw[ar * 128 + (((c ^ (ar & 7)) & 15) << 3)] = av[i];
        }
#pragma unroll
        for (int i = 0; i < 8; ++i) {
            const int c = bq * 8 + i;
            *(short8*)&Bsw[br * 128 + (((c ^ (br & 7)) & 15) << 3)] = bv[i];
        }
        __syncthreads();
#pragma unroll
        for (int ks = 0; ks < 4; ++ks) {
            const int ca = ((ks * 4 + quad) ^ (ln & 7)) & 15;
            const short8 a = *(const short8*)&Asw[(wave * 16 + ln) * 128 + (ca << 3)];
#pragma unroll
            for (int c = 0; c < 8; ++c) {
                const int rb = c * 16 + ln;
                const int cb = ((ks * 4 + quad) ^ (ln & 7)) & 15;
                const short8 b = *(const short8*)&Bsw[rb * 128 + (cb << 3)];
                acc[c] = __builtin_amdgcn_mfma_f32_16x16x32_bf16(a, b, acc[c], 0, 0, 0);
            }
        }
    }
#pragma unroll
    for (int c = 0; c < 8; ++c) {
#pragma unroll
        for (int rg = 0; rg < 4; ++rg) {
            const int row = m0 + wave * 16 + quad * 4 + rg;
            if (row < M)
                out[(size_t)row * 128 + c * 16 + ln] = acc[c][rg];
        }
    }
}

// Generic-K fallback (runtime loop bound), slow but correct
__global__ __launch_bounds__(256) void gemm_kernel_rt(
    const unsigned short* __restrict__ A, const unsigned short* __restrict__ Xb,
    const unsigned short* __restrict__ Bt, float* __restrict__ out,
    int M, int ktot)
{
    const int tid = threadIdx.x;
    const int wave = tid >> 6;
    const int lane = tid & 63;
    const int ln = lane & 15, quad = lane >> 4;
    const int m0 = blockIdx.x * 64 + wave * 16;
    int m = m0 + ln; if (m >= M) m = M - 1;
    const unsigned short* Arow = A + (size_t)m * (ktot - 128) + quad * 8;
    const unsigned short* Xrow = Xb + (size_t)m * 128 + quad * 8;
    const unsigned short* Bbase = Bt + (size_t)ln * ktot + quad * 8;

    f32x4 acc[8] = {};
    for (int kb = 0; kb < (ktot >> 5); ++kb) {
        const int k0 = kb << 5;
        const unsigned short* asrc = (k0 < ktot - 128) ? (Arow + k0) : (Xrow + (k0 - (ktot - 128)));
        const short8 a = *(const short8*)asrc;
#pragma unroll
        for (int c = 0; c < 8; ++c) {
            const short8 b = *(const short8*)(Bbase + (size_t)c * 16 * ktot + k0);
            acc[c] = __builtin_amdgcn_mfma_f32_16x16x32_bf16(a, b, acc[c], 0, 0, 0);
        }
    }
#pragma unroll
    for (int c = 0; c < 8; ++c) {
#pragma unroll
        for (int rg = 0; rg < 4; ++rg) {
            const int row = m0 + quad * 4 + rg;
            if (row < M) out[(size_t)row * 128 + c * 16 + ln] = acc[c][rg];
        }
    }
}

// ---------------------------------------------------------------------------
extern "C" void kernel_launch(void* const* d_in, const int* in_sizes, int n_in,
                              void* d_out, int out_size, void* d_ws, size_t ws_size,
                              hipStream_t stream) {
    const float* X        = (const float*)d_in[0];
    const float* W        = (const float*)d_in[1];
    const float* W0       = (const float*)d_in[2];
    const float* inv_norm = (const float*)d_in[3];
    const int*   esrc     = (const int*)d_in[4];
    const int*   edst     = (const int*)d_in[5];
    const int*   erel     = (const int*)d_in[6];
    float* out = (float*)d_out;

    const int N  = in_sizes[0] / 128;     // 50000
    const int E  = in_sizes[4];           // 800000
    const int R  = in_sizes[3] / N;       // 8
    const int KB = N * 8;                 // 400000 bins (dst*8+rel)
    const int ktot = (R + 1) * 128;       // 1152

    char* ws = (char*)d_ws;
    size_t off = 0;
    auto alloc = [&](size_t bytes) -> char* {
        char* p = ws + off; off = (off + bytes + 255) & ~(size_t)255; return p;
    };
    unsigned short* A         = (unsigned short*)alloc((size_t)N * R * 128 * 2); // 102.4 MB
    unsigned short* Xb        = (unsigned short*)alloc((size_t)N * 128 * 2);     // 12.8 MB
    unsigned short* Bt        = (unsigned short*)alloc((size_t)128 * ktot * 2);  // 0.3 MB
    int*            counts    = (int*)alloc((size_t)KB * 4);                     // 1.6 MB
    int*            offsets   = (int*)alloc((size_t)KB * 4);                     // 1.6 MB
    int*            starts    = (int*)alloc((size_t)KB * 4);                     // 1.6 MB
    int*            blockSums = (int*)alloc(512 * 4);
    unsigned*       sorted    = (unsigned*)alloc((size_t)E * 4);                 // 3.2 MB
    (void)ws_size;

    const int nScanBlocks = (KB + 1023) / 1024;   // 391 (<=512)

    hipMemsetAsync(counts, 0, (size_t)KB * 4, stream);
    hist_kernel<<<2048, 256, 0, stream>>>(edst, erel, counts, E);
    scan1_kernel<<<nScanBlocks, 256, 0, stream>>>(counts, blockSums, KB);
    scan2_kernel<<<1, 512, 0, stream>>>(blockSums, nScanBlocks);
    scan3_kernel<<<nScanBlocks, 256, 0, stream>>>(counts, blockSums, offsets, starts, KB);
    scatter_fill_kernel<<<2048, 256, 0, stream>>>(esrc, edst, erel, offsets, sorted, E);
    cast_kernel<<<(N * 32 + 128 * ktot + 255) / 256, 256, 0, stream>>>(X, W, W0, Xb, Bt, N, R);
    aggregate_kernel<<<(N + 3) / 4, 256, 0, stream>>>(Xb, inv_norm, sorted, starts, A, N, E);
    if (ktot == 1152)
        gemm_kernel<1152><<<(N + 63) / 64, 256, 0, stream>>>(A, Xb, Bt, out, N);
    else
        gemm_kernel_rt<<<(N + 63) / 64, 256, 0, stream>>>(A, Xb, Bt, out, N, ktot);
}